// Round 1
// baseline (498.710 us; speedup 1.0000x reference)
//
#include <hip/hip_runtime.h>
#include <stdint.h>

// Problem constants (B=8,T=8192,H=512,E=4,R=16)
#define NTOK 65536
#define HD   512
#define EXP  4
#define RK   16
#define BK   32

typedef __attribute__((ext_vector_type(8))) short short8;
typedef __attribute__((ext_vector_type(4))) float f32x4;

__device__ __forceinline__ unsigned short f2bf(float f) {
  union { float f; unsigned int u; } c; c.f = f;
  return (unsigned short)((c.u + 0x7fffu + ((c.u >> 16) & 1u)) >> 16);
}

// ---------------- bulk fp32 -> bf16 ----------------
__global__ void convk(const float* __restrict__ in, unsigned short* __restrict__ o, int n4) {
  int i = blockIdx.x * 256 + threadIdx.x;
  if (i < n4) {
    float4 v = ((const float4*)in)[i];
    ushort4 u;
    u.x = f2bf(v.x); u.y = f2bf(v.y); u.z = f2bf(v.z); u.w = f2bf(v.w);
    ((ushort4*)o)[i] = u;
  }
}

// ---------------- Mt[d][e*16+r] = sum_o lora_B[e,r,o] * fc2_w[e,d,o] ----------------
__global__ void prep_mt(const float* __restrict__ loraB, const float* __restrict__ fc2,
                        unsigned short* __restrict__ Mt) {
  int idx = blockIdx.x * 256 + threadIdx.x;  // 64*512 = 32768 threads
  int d  = idx & (HD - 1);
  int er = idx >> 9;
  int e = er >> 4, r = er & 15;
  const float4* B = (const float4*)(loraB + ((size_t)e * RK + r) * HD);
  const float4* F = (const float4*)(fc2 + ((size_t)e * HD + d) * HD);
  float a0 = 0.f, a1 = 0.f, a2 = 0.f, a3 = 0.f;
  for (int i = 0; i < HD / 4; i += 4) {
    float4 b0 = B[i],     f0 = F[i];
    float4 b1 = B[i + 1], f1 = F[i + 1];
    float4 b2 = B[i + 2], f2 = F[i + 2];
    float4 b3 = B[i + 3], f3 = F[i + 3];
    a0 += b0.x * f0.x + b0.y * f0.y + b0.z * f0.z + b0.w * f0.w;
    a1 += b1.x * f1.x + b1.y * f1.y + b1.z * f1.z + b1.w * f1.w;
    a2 += b2.x * f2.x + b2.y * f2.y + b2.z * f2.z + b2.w * f2.w;
    a3 += b3.x * f3.x + b3.y * f3.y + b3.z * f3.z + b3.w * f3.w;
  }
  Mt[d * 64 + er] = f2bf(a0 + a1 + a2 + a3);
}

// ---------------- gating: fp32, one wave per token ----------------
__global__ void gating_k(const float* __restrict__ x, const float* __restrict__ gw,
                         const float* __restrict__ tw, float* __restrict__ gates) {
  const int lane = threadIdx.x & 63;
  const int n = blockIdx.x * 4 + (threadIdx.x >> 6);
  const float4* xr = (const float4*)(x + (size_t)n * HD);
  const float4 xa = xr[lane * 2], xb = xr[lane * 2 + 1];
  float s[5];
#pragma unroll
  for (int e = 0; e < 4; e++) {
    const float4* wr = (const float4*)(gw + e * HD);
    const float4 wa = wr[lane * 2], wb = wr[lane * 2 + 1];
    s[e] = xa.x * wa.x + xa.y * wa.y + xa.z * wa.z + xa.w * wa.w
         + xb.x * wb.x + xb.y * wb.y + xb.z * wb.z + xb.w * wb.w;
  }
  {
    const float4* wr = (const float4*)tw;
    const float4 wa = wr[lane * 2], wb = wr[lane * 2 + 1];
    s[4] = xa.x * wa.x + xa.y * wa.y + xa.z * wa.z + xa.w * wa.w
         + xb.x * wb.x + xb.y * wb.y + xb.z * wb.z + xb.w * wb.w;
  }
#pragma unroll
  for (int off = 32; off > 0; off >>= 1)
#pragma unroll
    for (int i = 0; i < 5; i++) s[i] += __shfl_xor(s[i], off, 64);
  float m = fmaxf(fmaxf(s[0], s[1]), fmaxf(s[2], s[3]));
  float e0 = expf(s[0] - m), e1 = expf(s[1] - m), e2 = expf(s[2] - m), e3 = expf(s[3] - m);
  float inv = 1.f / (e0 + e1 + e2 + e3);
  float thr = 0.25f / (1.f + expf(-s[4]));
  float a0 = e0 * inv - thr, a1 = e1 * inv - thr, a2 = e2 * inv - thr, a3 = e3 * inv - thr;
  float w0 = a0 > 0.f ? a0 : 0.f, w1 = a1 > 0.f ? a1 : 0.f;
  float w2 = a2 > 0.f ? a2 : 0.f, w3 = a3 > 0.f ? a3 : 0.f;
  float wsum = w0 + w1 + w2 + w3;
  wsum = (wsum == 0.f) ? 1.f : wsum;
  if (lane < 4) {
    float wv = lane == 0 ? w0 : lane == 1 ? w1 : lane == 2 ? w2 : w3;
    gates[(size_t)n * 4 + lane] = wv / wsum;
  }
}

// ---------------- fused fc1 + relu + lora_A -> lw[N][64] (atomic fp32) ----------------
// block: 256 thr = 4 waves; tile: 128 tokens x 256 hidden (one expert, one h-half)
// wave (t,h) grid 2x2, wave tile 64 tok x 128 h. BK=32 double-buffered LDS (<=64KB).
__launch_bounds__(256, 2)
__global__ void fc1_lora(const unsigned short* __restrict__ xb,
                         const unsigned short* __restrict__ w1b,
                         const float* __restrict__ loraA,
                         float* __restrict__ lw) {
  __shared__ __align__(16) char smem[65536];
  // staging: xs[p] @ p*8192 (128 rows x 32 bf16); ws[p] @ 16384+p*16384 (256 rows x 32)
  // stage2 overlay: hs per wave @ wave*16384 (64 tok x 128 h bf16)
  const int e  = blockIdx.x;
  const int hh = blockIdx.y;            // h-half: 0/1 -> h base hh*256
  const int n0 = blockIdx.z * 128;
  const int tid = threadIdx.x;
  const int wave = tid >> 6, lane = tid & 63, quad = lane >> 4, l16 = lane & 15;

  const unsigned short* xg = xb + (size_t)n0 * HD;
  const unsigned short* wg = w1b + (size_t)e * HD * HD + (size_t)hh * 256 * HD;

  const int srow = tid >> 2;            // 0..63
  const int scol = (tid & 3) << 3;      // 0,8,16,24

  f32x4 acc[4][8];
#pragma unroll
  for (int a = 0; a < 4; a++)
#pragma unroll
    for (int b = 0; b < 8; b++) acc[a][b] = (f32x4){0.f, 0.f, 0.f, 0.f};

  // prologue: stage k=0 into buffer 0
  {
    short8 tx0 = *(const short8*)(xg + (size_t)srow * HD + scol);
    short8 tx1 = *(const short8*)(xg + (size_t)(srow + 64) * HD + scol);
    short8 tw0[4];
#pragma unroll
    for (int i = 0; i < 4; i++)
      tw0[i] = *(const short8*)(wg + (size_t)(srow + 64 * i) * HD + scol);
    *(short8*)(smem + (srow * BK + scol) * 2) = tx0;
    *(short8*)(smem + ((srow + 64) * BK + scol) * 2) = tx1;
#pragma unroll
    for (int i = 0; i < 4; i++)
      *(short8*)(smem + 16384 + ((srow + 64 * i) * BK + scol) * 2) = tw0[i];
  }
  __syncthreads();

  const int arow0 = (wave & 1) * 64;
  const int brow0 = (wave >> 1) * 128;

  for (int ks = 0; ks < HD / BK; ks++) {
    const int p = ks & 1;
    const bool more = (ks + 1 < HD / BK);
    short8 tx0, tx1, tw0[4];
    if (more) {
      const int k1 = (ks + 1) * BK;
      tx0 = *(const short8*)(xg + (size_t)srow * HD + k1 + scol);
      tx1 = *(const short8*)(xg + (size_t)(srow + 64) * HD + k1 + scol);
#pragma unroll
      for (int i = 0; i < 4; i++)
        tw0[i] = *(const short8*)(wg + (size_t)(srow + 64 * i) * HD + k1 + scol);
    }
    {
      const char* xs  = smem + p * 8192;
      const char* wsb = smem + 16384 + p * 16384;
      short8 af[4], bfr[8];
#pragma unroll
      for (int mf = 0; mf < 4; mf++)
        af[mf] = *(const short8*)(xs + ((arow0 + mf * 16 + l16) * BK + quad * 8) * 2);
#pragma unroll
      for (int nf = 0; nf < 8; nf++)
        bfr[nf] = *(const short8*)(wsb + ((brow0 + nf * 16 + l16) * BK + quad * 8) * 2);
#pragma unroll
      for (int mf = 0; mf < 4; mf++)
#pragma unroll
        for (int nf = 0; nf < 8; nf++)
          acc[mf][nf] = __builtin_amdgcn_mfma_f32_16x16x32_bf16(af[mf], bfr[nf], acc[mf][nf], 0, 0, 0);
    }
    if (more) {
      const int q = p ^ 1;
      *(short8*)(smem + q * 8192 + (srow * BK + scol) * 2) = tx0;
      *(short8*)(smem + q * 8192 + ((srow + 64) * BK + scol) * 2) = tx1;
#pragma unroll
      for (int i = 0; i < 4; i++)
        *(short8*)(smem + 16384 + q * 16384 + ((srow + 64 * i) * BK + scol) * 2) = tw0[i];
    }
    __syncthreads();
  }

  // stage 2: relu -> bf16 hidden into per-wave LDS, then lo = hidden @ lora_A slice
  char* hs = smem + wave * 16384;  // [64 tok][128 h] bf16
#pragma unroll
  for (int mf = 0; mf < 4; mf++)
#pragma unroll
    for (int nf = 0; nf < 8; nf++) {
      f32x4 v = acc[mf][nf];
      const int col = nf * 16 + l16;
#pragma unroll
      for (int i = 0; i < 4; i++) {
        float r = v[i] > 0.f ? v[i] : 0.f;
        ((unsigned short*)hs)[(mf * 16 + quad * 4 + i) * 128 + col] = f2bf(r);
      }
    }
  __syncthreads();

  const float* Ae = loraA + (size_t)e * HD * RK;
  const int hbase = hh * 256 + (wave >> 1) * 128;
  f32x4 lo[4];
#pragma unroll
  for (int mf = 0; mf < 4; mf++) lo[mf] = (f32x4){0.f, 0.f, 0.f, 0.f};
#pragma unroll
  for (int k2 = 0; k2 < 4; k2++) {
    short8 a2[4];
#pragma unroll
    for (int mf = 0; mf < 4; mf++)
      a2[mf] = *(const short8*)(hs + ((mf * 16 + l16) * 128 + k2 * 32 + quad * 8) * 2);
    union { short8 v; short s[8]; } b2;
#pragma unroll
    for (int j = 0; j < 8; j++)
      b2.s[j] = (short)f2bf(Ae[(size_t)(hbase + k2 * 32 + quad * 8 + j) * RK + l16]);
#pragma unroll
    for (int mf = 0; mf < 4; mf++)
      lo[mf] = __builtin_amdgcn_mfma_f32_16x16x32_bf16(a2[mf], b2.v, lo[mf], 0, 0, 0);
  }
  const int ntok0 = n0 + (wave & 1) * 64;
#pragma unroll
  for (int mf = 0; mf < 4; mf++)
#pragma unroll
    for (int i = 0; i < 4; i++)
      atomicAdd(lw + (size_t)(ntok0 + mf * 16 + quad * 4 + i) * 64 + e * 16 + l16, lo[mf][i]);
}

// ---------------- combine: out[n][d] = sum_k (lw[n][k]*gate[n][k/16]) * Mt[d][k] ----------------
// block: 64 tokens x 512 d; 4 waves each 64x128. Mt staged in LDS (64KB).
__launch_bounds__(256, 2)
__global__ void combine_k(const float* __restrict__ lw, const float* __restrict__ gates,
                          const unsigned short* __restrict__ Mt, float* __restrict__ out) {
  __shared__ __align__(16) char smem[65536];
  const int n0 = blockIdx.x * 64;
  const int tid = threadIdx.x;
  const int wave = tid >> 6, lane = tid & 63, quad = lane >> 4, l16 = lane & 15;
#pragma unroll
  for (int i = 0; i < 16; i++) {
    const int c = tid + 256 * i;
    *(uint4*)(smem + c * 16) = *(const uint4*)((const char*)Mt + c * 16);
  }
  __syncthreads();
  f32x4 acc[4][8];
#pragma unroll
  for (int a = 0; a < 4; a++)
#pragma unroll
    for (int b = 0; b < 8; b++) acc[a][b] = (f32x4){0.f, 0.f, 0.f, 0.f};
#pragma unroll
  for (int ks = 0; ks < 2; ks++) {
    short8 af[4], bfr[8];
#pragma unroll
    for (int mf = 0; mf < 4; mf++) {
      const int n = n0 + mf * 16 + l16;
      const float* lr = lw + (size_t)n * 64 + ks * 32 + quad * 8;
      float4 u0 = *(const float4*)lr;
      float4 u1 = *(const float4*)(lr + 4);
      const float g = gates[(size_t)n * 4 + ((ks * 32 + quad * 8) >> 4)];
      union { short8 v; short s[8]; } a;
      a.s[0] = (short)f2bf(u0.x * g); a.s[1] = (short)f2bf(u0.y * g);
      a.s[2] = (short)f2bf(u0.z * g); a.s[3] = (short)f2bf(u0.w * g);
      a.s[4] = (short)f2bf(u1.x * g); a.s[5] = (short)f2bf(u1.y * g);
      a.s[6] = (short)f2bf(u1.z * g); a.s[7] = (short)f2bf(u1.w * g);
      af[mf] = a.v;
    }
#pragma unroll
    for (int nf = 0; nf < 8; nf++)
      bfr[nf] = *(const short8*)(smem + ((wave * 128 + nf * 16 + l16) * 64 + ks * 32 + quad * 8) * 2);
#pragma unroll
    for (int mf = 0; mf < 4; mf++)
#pragma unroll
      for (int nf = 0; nf < 8; nf++)
        acc[mf][nf] = __builtin_amdgcn_mfma_f32_16x16x32_bf16(af[mf], bfr[nf], acc[mf][nf], 0, 0, 0);
  }
#pragma unroll
  for (int mf = 0; mf < 4; mf++)
#pragma unroll
    for (int nf = 0; nf < 8; nf++) {
      const int d = wave * 128 + nf * 16 + l16;
#pragma unroll
      for (int i = 0; i < 4; i++)
        out[(size_t)(n0 + mf * 16 + quad * 4 + i) * HD + d] = acc[mf][nf][i];
    }
}

// ---------------- launch ----------------
extern "C" void kernel_launch(void* const* d_in, const int* in_sizes, int n_in,
                              void* d_out, int out_size, void* d_ws, size_t ws_size,
                              hipStream_t stream) {
  const float* x      = (const float*)d_in[0];
  const float* gate_w = (const float*)d_in[1];
  const float* thr_w  = (const float*)d_in[2];
  const float* fc1_w  = (const float*)d_in[3];
  const float* lora_A = (const float*)d_in[4];
  const float* lora_B = (const float*)d_in[5];
  const float* fc2_w  = (const float*)d_in[6];
  float* out = (float*)d_out;
  char* ws = (char*)d_ws;

  unsigned short* xb  = (unsigned short*)(ws);                   // 67108864 B
  unsigned short* w1b = (unsigned short*)(ws + 67108864);        //  2097152 B
  unsigned short* Mt  = (unsigned short*)(ws + 69206016);        //    65536 B
  float*          gts = (float*)(ws + 69271552);                 //  1048576 B
  float*          lwp = (float*)(ws + 70320128);                 // 16777216 B

  hipMemsetAsync(lwp, 0, (size_t)NTOK * 64 * sizeof(float), stream);
  convk<<<32768, 256, 0, stream>>>(x, xb, NTOK * HD / 4);
  convk<<<1024, 256, 0, stream>>>(fc1_w, w1b, EXP * HD * HD / 4);
  prep_mt<<<128, 256, 0, stream>>>(lora_B, fc2_w, Mt);
  gating_k<<<NTOK / 4, 256, 0, stream>>>(x, gate_w, thr_w, gts);
  fc1_lora<<<dim3(EXP, 2, NTOK / 128), 256, 0, stream>>>(xb, w1b, lora_A, lwp);
  combine_k<<<NTOK / 64, 256, 0, stream>>>(lwp, gts, Mt, out);
}

// Round 2
// 469.544 us; speedup vs baseline: 1.0621x; 1.0621x over previous
//
#include <hip/hip_runtime.h>
#include <stdint.h>

// Problem constants (B=8,T=8192,H=512,E=4,R=16)
#define NTOK 65536
#define HD   512
#define EXP  4
#define RK   16
#define BK   32

typedef __attribute__((ext_vector_type(8)))  short short8;
typedef __attribute__((ext_vector_type(4)))  float f32x4;
typedef __attribute__((ext_vector_type(16))) float f32x16;

__device__ __forceinline__ unsigned short f2bf(float f) {
  union { float f; unsigned int u; } c; c.f = f;
  return (unsigned short)((c.u + 0x7fffu + ((c.u >> 16) & 1u)) >> 16);
}

__device__ __forceinline__ void gl_lds16(const void* g, void* l) {
  __builtin_amdgcn_global_load_lds((const __attribute__((address_space(1))) void*)g,
                                   (__attribute__((address_space(3))) void*)l, 16, 0, 0);
}

// ---------------- fused x fp32->bf16 + gating (reads x ONCE) ----------------
// one wave per token
__global__ void convgate(const float* __restrict__ x, const float* __restrict__ gw,
                         const float* __restrict__ tw, unsigned short* __restrict__ xbo,
                         float* __restrict__ gates) {
  const int lane = threadIdx.x & 63;
  const int n = blockIdx.x * 4 + (threadIdx.x >> 6);
  const float4* xr = (const float4*)(x + (size_t)n * HD);
  const float4 xa = xr[lane * 2], xb = xr[lane * 2 + 1];
  // bf16 write-out (16 B/lane, coalesced)
  ushort4 ua, ub;
  ua.x = f2bf(xa.x); ua.y = f2bf(xa.y); ua.z = f2bf(xa.z); ua.w = f2bf(xa.w);
  ub.x = f2bf(xb.x); ub.y = f2bf(xb.y); ub.z = f2bf(xb.z); ub.w = f2bf(xb.w);
  ushort4* xo = (ushort4*)(xbo + (size_t)n * HD);
  xo[lane * 2] = ua; xo[lane * 2 + 1] = ub;
  float s[5];
#pragma unroll
  for (int e = 0; e < 4; e++) {
    const float4* wr = (const float4*)(gw + e * HD);
    const float4 wa = wr[lane * 2], wb = wr[lane * 2 + 1];
    s[e] = xa.x * wa.x + xa.y * wa.y + xa.z * wa.z + xa.w * wa.w
         + xb.x * wb.x + xb.y * wb.y + xb.z * wb.z + xb.w * wb.w;
  }
  {
    const float4* wr = (const float4*)tw;
    const float4 wa = wr[lane * 2], wb = wr[lane * 2 + 1];
    s[4] = xa.x * wa.x + xa.y * wa.y + xa.z * wa.z + xa.w * wa.w
         + xb.x * wb.x + xb.y * wb.y + xb.z * wb.z + xb.w * wb.w;
  }
#pragma unroll
  for (int off = 32; off > 0; off >>= 1)
#pragma unroll
    for (int i = 0; i < 5; i++) s[i] += __shfl_xor(s[i], off, 64);
  float m = fmaxf(fmaxf(s[0], s[1]), fmaxf(s[2], s[3]));
  float e0 = expf(s[0] - m), e1 = expf(s[1] - m), e2 = expf(s[2] - m), e3 = expf(s[3] - m);
  float inv = 1.f / (e0 + e1 + e2 + e3);
  float thr = 0.25f / (1.f + expf(-s[4]));
  float a0 = e0 * inv - thr, a1 = e1 * inv - thr, a2 = e2 * inv - thr, a3 = e3 * inv - thr;
  float w0 = a0 > 0.f ? a0 : 0.f, w1 = a1 > 0.f ? a1 : 0.f;
  float w2 = a2 > 0.f ? a2 : 0.f, w3 = a3 > 0.f ? a3 : 0.f;
  float wsum = w0 + w1 + w2 + w3;
  wsum = (wsum == 0.f) ? 1.f : wsum;
  if (lane < 4) {
    float wv = lane == 0 ? w0 : lane == 1 ? w1 : lane == 2 ? w2 : w3;
    gates[(size_t)n * 4 + lane] = wv / wsum;
  }
}

// ---------------- bulk fp32 -> bf16 (fc1_w) ----------------
__global__ void convk(const float* __restrict__ in, unsigned short* __restrict__ o, int n4) {
  int i = blockIdx.x * 256 + threadIdx.x;
  if (i < n4) {
    float4 v = ((const float4*)in)[i];
    ushort4 u;
    u.x = f2bf(v.x); u.y = f2bf(v.y); u.z = f2bf(v.z); u.w = f2bf(v.w);
    ((ushort4*)o)[i] = u;
  }
}

// ---------------- Mt[d][e*16+r] = sum_o lora_B[e,r,o] * fc2_w[e,d,o] ----------------
__global__ void prep_mt(const float* __restrict__ loraB, const float* __restrict__ fc2,
                        unsigned short* __restrict__ Mt) {
  int idx = blockIdx.x * 256 + threadIdx.x;  // 64*512 = 32768 threads
  int d  = idx & (HD - 1);
  int er = idx >> 9;
  int e = er >> 4, r = er & 15;
  const float4* B = (const float4*)(loraB + ((size_t)e * RK + r) * HD);
  const float4* F = (const float4*)(fc2 + ((size_t)e * HD + d) * HD);
  float a0 = 0.f, a1 = 0.f, a2 = 0.f, a3 = 0.f;
  for (int i = 0; i < HD / 4; i += 4) {
    float4 b0 = B[i],     f0 = F[i];
    float4 b1 = B[i + 1], f1 = F[i + 1];
    float4 b2 = B[i + 2], f2 = F[i + 2];
    float4 b3 = B[i + 3], f3 = F[i + 3];
    a0 += b0.x * f0.x + b0.y * f0.y + b0.z * f0.z + b0.w * f0.w;
    a1 += b1.x * f1.x + b1.y * f1.y + b1.z * f1.z + b1.w * f1.w;
    a2 += b2.x * f2.x + b2.y * f2.y + b2.z * f2.z + b2.w * f2.w;
    a3 += b3.x * f3.x + b3.y * f3.y + b3.z * f3.z + b3.w * f3.w;
  }
  Mt[d * 64 + er] = f2bf(a0 + a1 + a2 + a3);
}

// ---------------- fused fc1 + relu + lora_A -> lw[N][64] (atomic fp32) ----------------
// m97-structure: 128 tok x 128 h block tile, 4 waves (2x2), 32x32x16 bf16 MFMA,
// single-buffer 2-barrier K-loop, global_load_lds width=16 staging with
// XOR-permuted granule placement (kills the 8-way ds_read conflicts).
__launch_bounds__(256, 3)
__global__ void fc1_lora(const unsigned short* __restrict__ xb,
                         const unsigned short* __restrict__ w1b,
                         const float* __restrict__ loraA,
                         float* __restrict__ lw) {
  __shared__ __align__(16) char smem[34816];  // stage1: 16 KB; stage2 hidden: 128x136 bf16
  // XCD-friendly decode: blocks sharing a token tile land on the same XCD
  const int bid = blockIdx.x;           // 8192 blocks
  const int c = bid & 7, s = bid >> 3;
  const int eh = s & 15;
  const int e = eh >> 2, hq = eh & 3;   // expert, h-quarter (128 h each)
  const int ntile = ((s >> 4) << 3) | c;
  const int n0 = ntile * 128;
  const int tid = threadIdx.x;
  const int wave = tid >> 6, lane = tid & 63;
  const int l16 = lane & 15, quad = lane >> 4;
  const int l32 = lane & 31, half = lane >> 5;

  const unsigned short* xg = xb + (size_t)n0 * HD;
  const unsigned short* wg = w1b + ((size_t)e * HD + (size_t)hq * 128) * HD;

  // staging source addresses: slot S -> row=S>>2, stored granule (S&3) holds src q=(S&3)^(row&3)
  const int slotA = tid, slotB = tid + 256;
  const int rA = slotA >> 2, qA = (slotA & 3) ^ (rA & 3);
  const int rB = slotB >> 2, qB = (slotB & 3) ^ (rB & 3);
  const unsigned short* xsA = xg + (size_t)rA * HD + qA * 8;
  const unsigned short* xsB = xg + (size_t)rB * HD + qB * 8;
  const unsigned short* wsA = wg + (size_t)rA * HD + qA * 8;
  const unsigned short* wsB = wg + (size_t)rB * HD + qB * 8;
  char* ldsx = smem;          // 8192 B (512 granules)
  char* ldsw = smem + 8192;   // 8192 B
  char* dxA = ldsx + (wave * 64) * 16;
  char* dxB = ldsx + (256 + wave * 64) * 16;
  char* dwA = ldsw + (wave * 64) * 16;
  char* dwB = ldsw + (256 + wave * 64) * 16;

  const int twave = (wave & 1) * 64;   // token half
  const int hwave = (wave >> 1) * 64;  // h half

  // loop-invariant LDS read offsets [kk][mb/nb]
  int axo[2][2], bxo[2][2];
#pragma unroll
  for (int kk = 0; kk < 2; kk++)
#pragma unroll
    for (int b = 0; b < 2; b++) {
      int rowa = twave + b * 32 + l32;
      axo[kk][b] = (rowa * 4 + ((kk * 2 + half) ^ (rowa & 3))) * 16;
      int rowb = hwave + b * 32 + l32;
      bxo[kk][b] = (rowb * 4 + ((kk * 2 + half) ^ (rowb & 3))) * 16;
    }

  f32x16 acc[2][2];
#pragma unroll
  for (int mb = 0; mb < 2; mb++)
#pragma unroll
    for (int nb = 0; nb < 2; nb++)
#pragma unroll
      for (int r = 0; r < 16; r++) acc[mb][nb][r] = 0.f;

  for (int ks = 0; ks < HD / BK; ks++) {
    const int ko = ks * BK;
    gl_lds16(xsA + ko, dxA);
    gl_lds16(xsB + ko, dxB);
    gl_lds16(wsA + ko, dwA);
    gl_lds16(wsB + ko, dwB);
    __syncthreads();   // drains vmcnt -> staged tile visible
#pragma unroll
    for (int kk = 0; kk < 2; kk++) {
      short8 af[2], bf[2];
#pragma unroll
      for (int mb = 0; mb < 2; mb++) af[mb] = *(const short8*)(ldsx + axo[kk][mb]);
#pragma unroll
      for (int nb = 0; nb < 2; nb++) bf[nb] = *(const short8*)(ldsw + bxo[kk][nb]);
#pragma unroll
      for (int mb = 0; mb < 2; mb++)
#pragma unroll
        for (int nb = 0; nb < 2; nb++)
          acc[mb][nb] = __builtin_amdgcn_mfma_f32_32x32x16_bf16(af[mb], bf[nb], acc[mb][nb], 0, 0, 0);
    }
    __syncthreads();   // protect LDS before next stage
  }

  // stage 2: relu -> bf16 hidden to block-shared LDS [128 tok][136 shorts] (272 B rows, 16B-aligned)
  unsigned short* hsm = (unsigned short*)smem;
#pragma unroll
  for (int mb = 0; mb < 2; mb++)
#pragma unroll
    for (int nb = 0; nb < 2; nb++) {
      const int colh = hwave + nb * 32 + l32;
#pragma unroll
      for (int r = 0; r < 16; r++) {
        const int tok = twave + mb * 32 + 4 * half + (r & 3) + 8 * (r >> 2);
        float v = acc[mb][nb][r];
        v = v > 0.f ? v : 0.f;
        hsm[tok * 136 + colh] = f2bf(v);
      }
    }
  __syncthreads();

  // lo[tok][r] over this block's 128 h; wave handles tokens wave*32..+31
  const float* Ae = loraA + (size_t)e * HD * RK;
  const int hA0 = hq * 128;
  f32x4 lo[2];
#pragma unroll
  for (int mf = 0; mf < 2; mf++)
#pragma unroll
    for (int i = 0; i < 4; i++) lo[mf][i] = 0.f;
#pragma unroll
  for (int k2 = 0; k2 < 4; k2++) {
    short8 a2[2];
#pragma unroll
    for (int mf = 0; mf < 2; mf++) {
      const int tok = wave * 32 + mf * 16 + l16;
      a2[mf] = *(const short8*)(hsm + tok * 136 + k2 * 32 + quad * 8);
    }
    union { short8 v; unsigned short s[8]; } b2;
#pragma unroll
    for (int j = 0; j < 8; j++)
      b2.s[j] = f2bf(Ae[(size_t)(hA0 + k2 * 32 + quad * 8 + j) * RK + l16]);
#pragma unroll
    for (int mf = 0; mf < 2; mf++)
      lo[mf] = __builtin_amdgcn_mfma_f32_16x16x32_bf16(a2[mf], b2.v, lo[mf], 0, 0, 0);
  }
#pragma unroll
  for (int mf = 0; mf < 2; mf++)
#pragma unroll
    for (int i = 0; i < 4; i++)
      atomicAdd(lw + (size_t)(n0 + wave * 32 + mf * 16 + quad * 4 + i) * 64 + e * 16 + l16, lo[mf][i]);
}

// ---------------- combine: out[n][d] = sum_k (lw[n][k]*gate[n][k/16]) * Mt[d][k] ----------------
// Mt staged into LDS with XOR-swizzled 16B granules (row stride 128 B was 16-way conflicted).
__launch_bounds__(256, 2)
__global__ void combine_k(const float* __restrict__ lw, const float* __restrict__ gates,
                          const unsigned short* __restrict__ Mt, float* __restrict__ out) {
  __shared__ __align__(16) char smem[65536];
  const int n0 = blockIdx.x * 64;
  const int tid = threadIdx.x;
  const int wave = tid >> 6, lane = tid & 63, quad = lane >> 4, l16 = lane & 15;
  // stage Mt [512 d][64 k] bf16: granule slot = row*8 + (g ^ (row&7))
#pragma unroll
  for (int i = 0; i < 16; i++) {
    const int slot = tid + 256 * i;          // 0..4095
    const int row = slot >> 3;
    const int g = (slot & 7) ^ (row & 7);
    *(uint4*)(smem + slot * 16) = *(const uint4*)(Mt + row * 64 + g * 8);
  }
  __syncthreads();
  f32x4 acc[4][8];
#pragma unroll
  for (int a = 0; a < 4; a++)
#pragma unroll
    for (int b = 0; b < 8; b++)
#pragma unroll
      for (int i = 0; i < 4; i++) acc[a][b][i] = 0.f;
#pragma unroll
  for (int ks = 0; ks < 2; ks++) {
    short8 af[4], bfr[8];
#pragma unroll
    for (int mf = 0; mf < 4; mf++) {
      const int n = n0 + mf * 16 + l16;
      const float* lr = lw + (size_t)n * 64 + ks * 32 + quad * 8;
      float4 u0 = *(const float4*)lr;
      float4 u1 = *(const float4*)(lr + 4);
      const float g = gates[(size_t)n * 4 + ((ks * 32 + quad * 8) >> 4)];
      union { short8 v; unsigned short s[8]; } a;
      a.s[0] = f2bf(u0.x * g); a.s[1] = f2bf(u0.y * g);
      a.s[2] = f2bf(u0.z * g); a.s[3] = f2bf(u0.w * g);
      a.s[4] = f2bf(u1.x * g); a.s[5] = f2bf(u1.y * g);
      a.s[6] = f2bf(u1.z * g); a.s[7] = f2bf(u1.w * g);
      af[mf] = a.v;
    }
#pragma unroll
    for (int nf = 0; nf < 8; nf++) {
      const int row = wave * 128 + nf * 16 + l16;
      const int slot = row * 8 + ((ks * 4 + quad) ^ (row & 7));
      bfr[nf] = *(const short8*)(smem + slot * 16);
    }
#pragma unroll
    for (int mf = 0; mf < 4; mf++)
#pragma unroll
      for (int nf = 0; nf < 8; nf++)
        acc[mf][nf] = __builtin_amdgcn_mfma_f32_16x16x32_bf16(af[mf], bfr[nf], acc[mf][nf], 0, 0, 0);
  }
#pragma unroll
  for (int mf = 0; mf < 4; mf++)
#pragma unroll
    for (int nf = 0; nf < 8; nf++) {
      const int d = wave * 128 + nf * 16 + l16;
#pragma unroll
      for (int i = 0; i < 4; i++)
        out[(size_t)(n0 + mf * 16 + quad * 4 + i) * HD + d] = acc[mf][nf][i];
    }
}

// ---------------- launch ----------------
extern "C" void kernel_launch(void* const* d_in, const int* in_sizes, int n_in,
                              void* d_out, int out_size, void* d_ws, size_t ws_size,
                              hipStream_t stream) {
  const float* x      = (const float*)d_in[0];
  const float* gate_w = (const float*)d_in[1];
  const float* thr_w  = (const float*)d_in[2];
  const float* fc1_w  = (const float*)d_in[3];
  const float* lora_A = (const float*)d_in[4];
  const float* lora_B = (const float*)d_in[5];
  const float* fc2_w  = (const float*)d_in[6];
  float* out = (float*)d_out;
  char* ws = (char*)d_ws;

  unsigned short* xbp = (unsigned short*)(ws);                   // 67108864 B
  unsigned short* w1b = (unsigned short*)(ws + 67108864);        //  2097152 B
  unsigned short* Mt  = (unsigned short*)(ws + 69206016);        //    65536 B
  float*          gts = (float*)(ws + 69271552);                 //  1048576 B
  float*          lwp = (float*)(ws + 70320128);                 // 16777216 B

  hipMemsetAsync(lwp, 0, (size_t)NTOK * 64 * sizeof(float), stream);
  convgate<<<NTOK / 4, 256, 0, stream>>>(x, gate_w, thr_w, xbp, gts);
  convk<<<1024, 256, 0, stream>>>(fc1_w, w1b, EXP * HD * HD / 4);
  prep_mt<<<128, 256, 0, stream>>>(lora_B, fc2_w, Mt);
  fc1_lora<<<8192, 256, 0, stream>>>(xbp, w1b, lora_A, lwp);
  combine_k<<<NTOK / 64, 256, 0, stream>>>(lwp, gts, Mt, out);
}

// Round 3
// 446.668 us; speedup vs baseline: 1.1165x; 1.0512x over previous
//
#include <hip/hip_runtime.h>
#include <stdint.h>

// Problem constants (B=8,T=8192,H=512,E=4,R=16)
#define NTOK 65536
#define HD   512
#define EXP  4
#define RK   16

typedef __attribute__((ext_vector_type(8)))  short short8;
typedef __attribute__((ext_vector_type(4)))  float f32x4;
typedef __attribute__((ext_vector_type(16))) float f32x16;

__device__ __forceinline__ unsigned short f2bf(float f) {
  union { float f; unsigned int u; } c; c.f = f;
  return (unsigned short)((c.u + 0x7fffu + ((c.u >> 16) & 1u)) >> 16);
}

__device__ __forceinline__ void gl_lds16(const void* g, void* l) {
  __builtin_amdgcn_global_load_lds((const __attribute__((address_space(1))) void*)g,
                                   (__attribute__((address_space(3))) void*)l, 16, 0, 0);
}

// ---------------- fused x fp32->bf16 + gating (reads x ONCE) ----------------
__global__ void convgate(const float* __restrict__ x, const float* __restrict__ gw,
                         const float* __restrict__ tw, unsigned short* __restrict__ xbo,
                         float* __restrict__ gates) {
  const int lane = threadIdx.x & 63;
  const int n = blockIdx.x * 4 + (threadIdx.x >> 6);
  const float4* xr = (const float4*)(x + (size_t)n * HD);
  const float4 xa = xr[lane * 2], xb = xr[lane * 2 + 1];
  ushort4 ua, ub;
  ua.x = f2bf(xa.x); ua.y = f2bf(xa.y); ua.z = f2bf(xa.z); ua.w = f2bf(xa.w);
  ub.x = f2bf(xb.x); ub.y = f2bf(xb.y); ub.z = f2bf(xb.z); ub.w = f2bf(xb.w);
  ushort4* xo = (ushort4*)(xbo + (size_t)n * HD);
  xo[lane * 2] = ua; xo[lane * 2 + 1] = ub;
  float s[5];
#pragma unroll
  for (int e = 0; e < 4; e++) {
    const float4* wr = (const float4*)(gw + e * HD);
    const float4 wa = wr[lane * 2], wb = wr[lane * 2 + 1];
    s[e] = xa.x * wa.x + xa.y * wa.y + xa.z * wa.z + xa.w * wa.w
         + xb.x * wb.x + xb.y * wb.y + xb.z * wb.z + xb.w * wb.w;
  }
  {
    const float4* wr = (const float4*)tw;
    const float4 wa = wr[lane * 2], wb = wr[lane * 2 + 1];
    s[4] = xa.x * wa.x + xa.y * wa.y + xa.z * wa.z + xa.w * wa.w
         + xb.x * wb.x + xb.y * wb.y + xb.z * wb.z + xb.w * wb.w;
  }
#pragma unroll
  for (int off = 32; off > 0; off >>= 1)
#pragma unroll
    for (int i = 0; i < 5; i++) s[i] += __shfl_xor(s[i], off, 64);
  float m = fmaxf(fmaxf(s[0], s[1]), fmaxf(s[2], s[3]));
  float e0 = expf(s[0] - m), e1 = expf(s[1] - m), e2 = expf(s[2] - m), e3 = expf(s[3] - m);
  float inv = 1.f / (e0 + e1 + e2 + e3);
  float thr = 0.25f / (1.f + expf(-s[4]));
  float a0 = e0 * inv - thr, a1 = e1 * inv - thr, a2 = e2 * inv - thr, a3 = e3 * inv - thr;
  float w0 = a0 > 0.f ? a0 : 0.f, w1 = a1 > 0.f ? a1 : 0.f;
  float w2 = a2 > 0.f ? a2 : 0.f, w3 = a3 > 0.f ? a3 : 0.f;
  float wsum = w0 + w1 + w2 + w3;
  wsum = (wsum == 0.f) ? 1.f : wsum;
  if (lane < 4) {
    float wv = lane == 0 ? w0 : lane == 1 ? w1 : lane == 2 ? w2 : w3;
    gates[(size_t)n * 4 + lane] = wv / wsum;
  }
}

// ---------------- bulk fp32 -> bf16 (fc1_w) ----------------
__global__ void convk(const float* __restrict__ in, unsigned short* __restrict__ o, int n4) {
  int i = blockIdx.x * 256 + threadIdx.x;
  if (i < n4) {
    float4 v = ((const float4*)in)[i];
    ushort4 u;
    u.x = f2bf(v.x); u.y = f2bf(v.y); u.z = f2bf(v.z); u.w = f2bf(v.w);
    ((ushort4*)o)[i] = u;
  }
}

// ---------------- Mt[d][e*16+r] = sum_o lora_B[e,r,o] * fc2_w[e,d,o] ----------------
__global__ void prep_mt(const float* __restrict__ loraB, const float* __restrict__ fc2,
                        unsigned short* __restrict__ Mt) {
  int idx = blockIdx.x * 256 + threadIdx.x;  // 64*512 = 32768 threads
  int d  = idx & (HD - 1);
  int er = idx >> 9;
  int e = er >> 4, r = er & 15;
  const float4* B = (const float4*)(loraB + ((size_t)e * RK + r) * HD);
  const float4* F = (const float4*)(fc2 + ((size_t)e * HD + d) * HD);
  float a0 = 0.f, a1 = 0.f, a2 = 0.f, a3 = 0.f;
  for (int i = 0; i < HD / 4; i += 4) {
    float4 b0 = B[i],     f0 = F[i];
    float4 b1 = B[i + 1], f1 = F[i + 1];
    float4 b2 = B[i + 2], f2 = F[i + 2];
    float4 b3 = B[i + 3], f3 = F[i + 3];
    a0 += b0.x * f0.x + b0.y * f0.y + b0.z * f0.z + b0.w * f0.w;
    a1 += b1.x * f1.x + b1.y * f1.y + b1.z * f1.z + b1.w * f1.w;
    a2 += b2.x * f2.x + b2.y * f2.y + b2.z * f2.z + b2.w * f2.w;
    a3 += b3.x * f3.x + b3.y * f3.y + b3.z * f3.z + b3.w * f3.w;
  }
  Mt[d * 64 + er] = f2bf(a0 + a1 + a2 + a3);
}

// ---------------- fused fc1 + relu + lora_A -> lw[N][64] (atomic fp32) ----------------
// 128 tok x 128 h block tile, 4 waves (2x2 of 64x64), 32x32x16 bf16 MFMA.
// BK=64: LDS layout slot = row*8 + (g ^ (row&7)) -> full-period XOR:
//   staging: 8 consecutive lanes cover one row's 128-B k-window (coalesced global,
//   consecutive LDS granules); ds_read_b128 phases hit all 8 bank groups (0 conflicts).
__launch_bounds__(256, 4)
__global__ void fc1_lora(const unsigned short* __restrict__ xb,
                         const unsigned short* __restrict__ w1b,
                         const float* __restrict__ loraA,
                         float* __restrict__ lw) {
  __shared__ __align__(16) char smem[34816];  // stage1: 2x16KB; stage2: 128x136 bf16
  // XCD-friendly decode: blocks sharing a token tile land on the same XCD
  const int bid = blockIdx.x;           // 8192 blocks
  const int c = bid & 7, s = bid >> 3;
  const int eh = s & 15;
  const int e = eh >> 2, hq = eh & 3;   // expert, h-quarter (128 h each)
  const int ntile = ((s >> 4) << 3) | c;
  const int n0 = ntile * 128;
  const int tid = threadIdx.x;
  const int wave = tid >> 6, lane = tid & 63;
  const int l16 = lane & 15, quad = lane >> 4;
  const int l32 = lane & 31, half = lane >> 5;

  const unsigned short* xg = xb + (size_t)n0 * HD;
  const unsigned short* wg = w1b + ((size_t)e * HD + (size_t)hq * 128) * HD;

  char* ldsx = smem;           // 16 KB (1024 granules, [128 rows][8 g] XOR-swizzled)
  char* ldsw = smem + 16384;   // 16 KB

  // staging source addresses: slot S = tid + 256*i; row=S>>3, src granule g=(S&7)^(row&7)
  const unsigned short* xsrc[4];
  const unsigned short* wsrc[4];
#pragma unroll
  for (int i = 0; i < 4; i++) {
    const int sl = tid + 256 * i;
    const int row = sl >> 3, g = (sl & 7) ^ (row & 7);
    xsrc[i] = xg + (size_t)row * HD + g * 8;
    wsrc[i] = wg + (size_t)row * HD + g * 8;
  }

  const int twave = (wave & 1) * 64;   // token half
  const int hwave = (wave >> 1) * 64;  // h half

  // loop-invariant LDS read offsets: granule kk*2+half of row
  int axo[4][2], bxo[4][2];
#pragma unroll
  for (int kk = 0; kk < 4; kk++)
#pragma unroll
    for (int b = 0; b < 2; b++) {
      const int rowa = twave + b * 32 + l32;
      axo[kk][b] = (rowa * 8 + ((kk * 2 + half) ^ (rowa & 7))) * 16;
      const int rowb = hwave + b * 32 + l32;
      bxo[kk][b] = (rowb * 8 + ((kk * 2 + half) ^ (rowb & 7))) * 16;
    }

  f32x16 acc[2][2];
#pragma unroll
  for (int mb = 0; mb < 2; mb++)
#pragma unroll
    for (int nb = 0; nb < 2; nb++)
#pragma unroll
      for (int r = 0; r < 16; r++) acc[mb][nb][r] = 0.f;

  for (int ks = 0; ks < 8; ks++) {
    const int ko = ks * 64;
#pragma unroll
    for (int i = 0; i < 4; i++) {
      gl_lds16(xsrc[i] + ko, ldsx + (256 * i + wave * 64) * 16);
      gl_lds16(wsrc[i] + ko, ldsw + (256 * i + wave * 64) * 16);
    }
    __syncthreads();   // drains vmcnt -> staged tile visible
#pragma unroll
    for (int kk = 0; kk < 4; kk++) {
      short8 af[2], bf[2];
#pragma unroll
      for (int mb = 0; mb < 2; mb++) af[mb] = *(const short8*)(ldsx + axo[kk][mb]);
#pragma unroll
      for (int nb = 0; nb < 2; nb++) bf[nb] = *(const short8*)(ldsw + bxo[kk][nb]);
#pragma unroll
      for (int mb = 0; mb < 2; mb++)
#pragma unroll
        for (int nb = 0; nb < 2; nb++)
          acc[mb][nb] = __builtin_amdgcn_mfma_f32_32x32x16_bf16(af[mb], bf[nb], acc[mb][nb], 0, 0, 0);
    }
    __syncthreads();   // protect LDS before next stage
  }

  // stage 2: relu -> bf16 hidden to block-shared LDS [128 tok][136 shorts]
  unsigned short* hsm = (unsigned short*)smem;
#pragma unroll
  for (int mb = 0; mb < 2; mb++)
#pragma unroll
    for (int nb = 0; nb < 2; nb++) {
      const int colh = hwave + nb * 32 + l32;
#pragma unroll
      for (int r = 0; r < 16; r++) {
        const int tok = twave + mb * 32 + 4 * half + (r & 3) + 8 * (r >> 2);
        float v = acc[mb][nb][r];
        v = v > 0.f ? v : 0.f;
        hsm[tok * 136 + colh] = f2bf(v);
      }
    }
  __syncthreads();

  // lo[tok][r] over this block's 128 h; wave handles tokens wave*32..+31
  const float* Ae = loraA + (size_t)e * HD * RK;
  const int hA0 = hq * 128;
  f32x4 lo[2];
#pragma unroll
  for (int mf = 0; mf < 2; mf++)
#pragma unroll
    for (int i = 0; i < 4; i++) lo[mf][i] = 0.f;
#pragma unroll
  for (int k2 = 0; k2 < 4; k2++) {
    short8 a2[2];
#pragma unroll
    for (int mf = 0; mf < 2; mf++) {
      const int tok = wave * 32 + mf * 16 + l16;
      a2[mf] = *(const short8*)(hsm + tok * 136 + k2 * 32 + quad * 8);
    }
    union { short8 v; unsigned short s[8]; } b2;
#pragma unroll
    for (int j = 0; j < 8; j++)
      b2.s[j] = f2bf(Ae[(size_t)(hA0 + k2 * 32 + quad * 8 + j) * RK + l16]);
#pragma unroll
    for (int mf = 0; mf < 2; mf++)
      lo[mf] = __builtin_amdgcn_mfma_f32_16x16x32_bf16(a2[mf], b2.v, lo[mf], 0, 0, 0);
  }
#pragma unroll
  for (int mf = 0; mf < 2; mf++)
#pragma unroll
    for (int i = 0; i < 4; i++)
      atomicAdd(lw + (size_t)(n0 + wave * 32 + mf * 16 + quad * 4 + i) * 64 + e * 16 + l16, lo[mf][i]);
}

// ---------------- combine: out[n][d] = sum_k (lw[n][k]*gate[n][k/16]) * Mt[d][k] ----------------
// Mt staged into LDS with full-period XOR-swizzled 16B granules (conflict-free).
__launch_bounds__(256, 2)
__global__ void combine_k(const float* __restrict__ lw, const float* __restrict__ gates,
                          const unsigned short* __restrict__ Mt, float* __restrict__ out) {
  __shared__ __align__(16) char smem[65536];
  const int n0 = blockIdx.x * 64;
  const int tid = threadIdx.x;
  const int wave = tid >> 6, lane = tid & 63, quad = lane >> 4, l16 = lane & 15;
#pragma unroll
  for (int i = 0; i < 16; i++) {
    const int slot = tid + 256 * i;          // 0..4095
    const int row = slot >> 3;
    const int g = (slot & 7) ^ (row & 7);
    *(uint4*)(smem + slot * 16) = *(const uint4*)(Mt + row * 64 + g * 8);
  }
  __syncthreads();
  f32x4 acc[4][8];
#pragma unroll
  for (int a = 0; a < 4; a++)
#pragma unroll
    for (int b = 0; b < 8; b++)
#pragma unroll
      for (int i = 0; i < 4; i++) acc[a][b][i] = 0.f;
#pragma unroll
  for (int ks = 0; ks < 2; ks++) {
    short8 af[4], bfr[8];
#pragma unroll
    for (int mf = 0; mf < 4; mf++) {
      const int n = n0 + mf * 16 + l16;
      const float* lr = lw + (size_t)n * 64 + ks * 32 + quad * 8;
      float4 u0 = *(const float4*)lr;
      float4 u1 = *(const float4*)(lr + 4);
      const float g = gates[(size_t)n * 4 + ((ks * 32 + quad * 8) >> 4)];
      union { short8 v; unsigned short s[8]; } a;
      a.s[0] = f2bf(u0.x * g); a.s[1] = f2bf(u0.y * g);
      a.s[2] = f2bf(u0.z * g); a.s[3] = f2bf(u0.w * g);
      a.s[4] = f2bf(u1.x * g); a.s[5] = f2bf(u1.y * g);
      a.s[6] = f2bf(u1.z * g); a.s[7] = f2bf(u1.w * g);
      af[mf] = a.v;
    }
#pragma unroll
    for (int nf = 0; nf < 8; nf++) {
      const int row = wave * 128 + nf * 16 + l16;
      const int slot = row * 8 + ((ks * 4 + quad) ^ (row & 7));
      bfr[nf] = *(const short8*)(smem + slot * 16);
    }
#pragma unroll
    for (int mf = 0; mf < 4; mf++)
#pragma unroll
      for (int nf = 0; nf < 8; nf++)
        acc[mf][nf] = __builtin_amdgcn_mfma_f32_16x16x32_bf16(af[mf], bfr[nf], acc[mf][nf], 0, 0, 0);
  }
#pragma unroll
  for (int mf = 0; mf < 4; mf++)
#pragma unroll
    for (int nf = 0; nf < 8; nf++) {
      const int d = wave * 128 + nf * 16 + l16;
#pragma unroll
      for (int i = 0; i < 4; i++)
        out[(size_t)(n0 + mf * 16 + quad * 4 + i) * HD + d] = acc[mf][nf][i];
    }
}

// ---------------- launch ----------------
extern "C" void kernel_launch(void* const* d_in, const int* in_sizes, int n_in,
                              void* d_out, int out_size, void* d_ws, size_t ws_size,
                              hipStream_t stream) {
  const float* x      = (const float*)d_in[0];
  const float* gate_w = (const float*)d_in[1];
  const float* thr_w  = (const float*)d_in[2];
  const float* fc1_w  = (const float*)d_in[3];
  const float* lora_A = (const float*)d_in[4];
  const float* lora_B = (const float*)d_in[5];
  const float* fc2_w  = (const float*)d_in[6];
  float* out = (float*)d_out;
  char* ws = (char*)d_ws;

  unsigned short* xbp = (unsigned short*)(ws);                   // 67108864 B
  unsigned short* w1b = (unsigned short*)(ws + 67108864);        //  2097152 B
  unsigned short* Mt  = (unsigned short*)(ws + 69206016);        //    65536 B
  float*          gts = (float*)(ws + 69271552);                 //  1048576 B
  float*          lwp = (float*)(ws + 70320128);                 // 16777216 B

  hipMemsetAsync(lwp, 0, (size_t)NTOK * 64 * sizeof(float), stream);
  convgate<<<NTOK / 4, 256, 0, stream>>>(x, gate_w, thr_w, xbp, gts);
  convk<<<1024, 256, 0, stream>>>(fc1_w, w1b, EXP * HD * HD / 4);
  prep_mt<<<128, 256, 0, stream>>>(lora_B, fc2_w, Mt);
  fc1_lora<<<8192, 256, 0, stream>>>(xbp, w1b, lora_A, lwp);
  combine_k<<<NTOK / 64, 256, 0, stream>>>(lwp, gts, Mt, out);
}